// Round 4
// baseline (13354.654 us; speedup 1.0000x reference)
//
#include <hip/hip_runtime.h>
#include <hip/hip_cooperative_groups.h>

#define GN    128
#define GBIG  1.0e5f
#define NITER 128

// Padded layout: x pitch 128 (16B-aligned float4 rows), y,z padded to 130
// with BIG boundary planes. Interior at y,z in [1,128].
#define PPY     130
#define PITCH_Y 128
#define PITCH_Z (128 * 130)
#define PADDED_TOTAL (130 * 130 * 128)

// ---------------------------------------------------------------------------
// init: build padded uA, uB (both: culled regions rely on init values) and fP
// ---------------------------------------------------------------------------
__global__ __launch_bounds__(256) void eik_init(const float* __restrict__ u0,
                                                const float* __restrict__ f,
                                                float* __restrict__ uA,
                                                float* __restrict__ uB,
                                                float* __restrict__ fP) {
    const int i = blockIdx.x * 256 + threadIdx.x;
    if (i >= PADDED_TOTAL) return;
    const int x = i & 127;
    const int r = i >> 7;          // r = z*130 + y
    const int y = r % 130;
    const int z = r / 130;
    float uv = GBIG, fv = 0.0f;
    if (y >= 1 && y <= GN && z >= 1 && z <= GN) {
        const int src = ((z - 1) * GN + (y - 1)) * GN + x;
        uv = u0[src];
        fv = f[src];
    }
    uA[i] = uv;
    uB[i] = uv;
    fP[i] = fv;
}

__device__ __forceinline__ float eik_solve(float ax, float ay, float az,
                                           float fh, float uc) {
    const float a1 = fminf(fminf(ax, ay), az);
    const float a3 = fmaxf(fmaxf(ax, ay), az);
    const float a2 = fmaxf(fminf(fmaxf(ax, ay), az), fminf(ax, ay));
    const float x1 = a1 + fh;
    const float d12 = a1 - a2;
    const float disc2 = 2.0f * fh * fh - d12 * d12;
    const float x2 = 0.5f * (a1 + a2 + sqrtf(fmaxf(disc2, 0.0f)));
    const float s = a1 + a2 + a3;
    const float q = a1 * a1 + a2 * a2 + a3 * a3;
    const float disc3 = s * s - 3.0f * (q - fh * fh);
    const float x3 = (s + sqrtf(fmaxf(disc3, 0.0f))) * (1.0f / 3.0f);
    const float xv = (x1 <= a2) ? x1 : ((x2 <= a3) ? x2 : x3);
    return fminf(uc, xv);
}

__device__ __forceinline__ float4 eik_solve4(float4 c, float xm_s, float xp_s,
                                             float4 ym, float4 yp,
                                             float4 zm, float4 zp, float4 f4) {
    float4 r;
    r.x = eik_solve(fminf(xm_s, c.y), fminf(ym.x, yp.x), fminf(zm.x, zp.x), f4.x, c.x);
    r.y = eik_solve(fminf(c.x, c.z), fminf(ym.y, yp.y), fminf(zm.y, zp.y), f4.y, c.y);
    r.z = eik_solve(fminf(c.y, c.w), fminf(ym.z, yp.z), fminf(zm.z, zp.z), f4.z, c.z);
    r.w = eik_solve(fminf(c.z, xp_s), fminf(ym.w, yp.w), fminf(zm.w, zp.w), f4.w, c.w);
    return r;
}

// ---------------------------------------------------------------------------
// Cooperative persistent kernel: 128 sweeps + final compact write.
// block (32,8,1); grid (1,16,32) = 512 blocks -> needs only 2 blocks/CU
// (launch_bounds(256,2) caps VGPR at 256: large occupancy slack, coop launch
// cannot hit the TooLarge error that killed R2's 1024-block version).
// Each thread owns 4 z-planes x float4 = 16 cells, register-resident.
// Jacobi preserved: z-links between own planes use PRE-update values.
// ---------------------------------------------------------------------------
__global__ __launch_bounds__(256, 2) void eik_coop(const float* __restrict__ fP,
                                                   float* __restrict__ uA,
                                                   float* __restrict__ uB,
                                                   float* __restrict__ out) {
    cooperative_groups::grid_group grid = cooperative_groups::this_grid();

    const int lx  = threadIdx.x;                   // 0..31, 4 x-cells each
    const int gy  = blockIdx.y * 8 + threadIdx.y;  // 0..127
    const int gz0 = blockIdx.z * 4;                // planes gz0 .. gz0+3

    const int x0  = 4 * lx;
    const int dxm = (x0 <= 64 && 64 <= x0 + 3) ? 0
                        : min(abs(x0 - 64), abs(x0 + 3 - 64));
    const int dy = abs(gy - 64);
    int dz[4], dmin = 1 << 30;
    #pragma unroll
    for (int k = 0; k < 4; ++k) {
        dz[k] = dxm + dy + abs(gz0 + k - 64);   // L1 dist of plane-k cells
        dmin = min(dmin, dz[k]);
    }

    const int base0 = ((gz0 + 1) * PPY + (gy + 1)) * PITCH_Y + x0;

    float4 c[4], f4[4];
    #pragma unroll
    for (int k = 0; k < 4; ++k) {
        c[k]  = *(const float4*)(uA + base0 + k * PITCH_Z);
        f4[k] = *(const float4*)(fP + base0 + k * PITCH_Z);
    }

    for (int i = 1; i <= NITER; ++i) {
        // Wave-level cull (exact): after i sweeps only cells with L1 distance
        // <= i from the source can differ from init. Whole-wave skip keeps
        // shuffle lanes defined when any lane works.
        if (__any(dmin <= i)) {
            const float* uin = (i & 1) ? uA : uB;
            float* uout      = (i & 1) ? uB : uA;

            // x-halos via shuffle of PRE-update values, all lanes, all planes.
            float xm[4], xp[4];
            #pragma unroll
            for (int k = 0; k < 4; ++k) {
                xm[k] = __shfl_up(c[k].w, 1);
                xp[k] = __shfl_down(c[k].x, 1);
                if (lx == 0)  xm[k] = GBIG;
                if (lx == 31) xp[k] = GBIG;
            }

            float4 prev_old = make_float4(0.f, 0.f, 0.f, 0.f); // old plane k-1
            #pragma unroll
            for (int k = 0; k < 4; ++k) {
                const float4 old_k = c[k];
                if (dz[k] <= i) {
                    const int b = base0 + k * PITCH_Z;
                    const float4 ym = *(const float4*)(uin + b - PITCH_Y);
                    const float4 yp = *(const float4*)(uin + b + PITCH_Y);
                    const float4 zm = (k == 0)
                        ? *(const float4*)(uin + b - PITCH_Z) : prev_old;
                    const float4 zp = (k == 3)
                        ? *(const float4*)(uin + b + PITCH_Z) : c[k + 1];
                    c[k] = eik_solve4(old_k, xm[k], xp[k], ym, yp, zm, zp, f4[k]);
                    *(float4*)(uout + b) = c[k];
                }
                prev_old = old_k;   // PRE-update value for plane k+1's zm
            }
        }
        __threadfence();   // release stores device-wide (cross-XCD) pre-barrier
        grid.sync();
    }

    // Final state lives in registers — write compact 128^3 output directly.
    #pragma unroll
    for (int k = 0; k < 4; ++k)
        *(float4*)(out + ((gz0 + k) * GN + gy) * GN + x0) = c[k];
}

// ---------------------------------------------------------------------------
// Fallback path (proven in R1): one launch per sweep + extract.
// ---------------------------------------------------------------------------
__global__ __launch_bounds__(256) void eik_step(const float* __restrict__ uin,
                                                const float* __restrict__ fP,
                                                float* __restrict__ uout,
                                                int iter) {
    const int lx = threadIdx.x;
    const int gy = blockIdx.y * 8 + threadIdx.y;
    const int gz = blockIdx.z;
    const int x0 = 4 * lx;
    const int dxm = (x0 <= 64 && 64 <= x0 + 3) ? 0
                        : min(abs(x0 - 64), abs(x0 + 3 - 64));
    const int d = dxm + abs(gy - 64) + abs(gz - 64);
    if (d > iter) return;

    const int base = ((gz + 1) * PPY + (gy + 1)) * PITCH_Y + x0;
    const float4 cc = *(const float4*)(uin + base);
    float xm_s = uin[base - 1];
    float xp_s = uin[base + 4];
    if (lx == 0)  xm_s = GBIG;
    if (lx == 31) xp_s = GBIG;
    const float4 ym = *(const float4*)(uin + base - PITCH_Y);
    const float4 yp = *(const float4*)(uin + base + PITCH_Y);
    const float4 zm = *(const float4*)(uin + base - PITCH_Z);
    const float4 zp = *(const float4*)(uin + base + PITCH_Z);
    const float4 ff = *(const float4*)(fP + base);
    *(float4*)(uout + base) = eik_solve4(cc, xm_s, xp_s, ym, yp, zm, zp, ff);
}

__global__ __launch_bounds__(256) void eik_extract(const float* __restrict__ uf,
                                                   float* __restrict__ out) {
    const int j = blockIdx.x * 256 + threadIdx.x;
    const int x4 = j & 31;
    const int y  = (j >> 5) & 127;
    const int z  = j >> 12;
    const float4 v =
        *(const float4*)(uf + ((z + 1) * PPY + (y + 1)) * PITCH_Y + 4 * x4);
    *(float4*)(out + 4 * j) = v;
}

extern "C" void kernel_launch(void* const* d_in, const int* in_sizes, int n_in,
                              void* d_out, int out_size, void* d_ws, size_t ws_size,
                              hipStream_t stream) {
    const float* u0 = (const float*)d_in[0];
    const float* f  = (const float*)d_in[1];
    float* out = (float*)d_out;

    float* uA = (float*)d_ws;                    // 8.65 MB each
    float* uB = uA + PADDED_TOTAL;
    float* fP = uB + PADDED_TOTAL;

    {
        const int nb = (PADDED_TOTAL + 255) / 256;
        eik_init<<<nb, 256, 0, stream>>>(u0, f, uA, uB, fP);
    }

    // Capture-safe host-side metadata query (same result every call).
    int maxBlocksPerCU = 0;
    hipError_t qerr = hipOccupancyMaxActiveBlocksPerMultiprocessor(
        &maxBlocksPerCU, eik_coop, 256, 0);

    bool coop_ok = false;
    if (qerr == hipSuccess && maxBlocksPerCU >= 2) {
        dim3 grid(1, 16, 32);      // 512 blocks: needs just 2 blocks/CU
        dim3 block(32, 8, 1);
        void* args[] = {(void*)&fP, (void*)&uA, (void*)&uB, (void*)&out};
        hipError_t lerr = hipLaunchCooperativeKernel(
            (const void*)eik_coop, grid, block, args, 0, stream);
        coop_ok = (lerr == hipSuccess);
    }

    if (!coop_ok) {
        // Fallback: R1's proven multi-launch path.
        const dim3 block(32, 8, 1);
        const dim3 grid(1, 16, 128);
        for (int i = 1; i <= NITER; ++i) {
            const float* in = (i & 1) ? uA : uB;
            float* o        = (i & 1) ? uB : uA;
            eik_step<<<grid, block, 0, stream>>>(in, fP, o, i);
        }
        eik_extract<<<GN * GN * GN / 4 / 256, 256, 0, stream>>>(uA, out);
    }
}

// Round 6
// 1660.792 us; speedup vs baseline: 8.0411x; 8.0411x over previous
//
#include <hip/hip_runtime.h>

#define GN    128
#define GBIG  1.0e5f
#define NITER 128

// Padded layout: x pitch 128 (contiguous rows, no x padding), y,z padded to
// 132 with TWO planes of BIG each side (T=2 fusion needs a +/-2 window).
// Interior cell (x,y,z) -> ((z+2)*132 + (y+2))*128 + x.
#define PPY     132
#define PITCH_Y 128
#define PITCH_Z (128 * 132)
#define PADDED_TOTAL (132 * 132 * 128)

// Fused-kernel tile: 64 x 16 x 4 cells per block, 512 blocks, 2 blocks/CU.
// LDS input region: x window 72 (x0-4..x0+67), y 20, z 8.
#define W_IN 72
#define H_IN 20
#define D_IN 8
#define N_IN (W_IN * H_IN * D_IN)          // 11520 floats
// Step-1 result region: x 68 (x0-2..x0+65), y 18, z 6.
#define W1 68
#define H1 18
#define D1 6
#define LDS_BYTES ((N_IN + W1 * H1 * D1) * 4)   // 75456 B

// ---------------------------------------------------------------------------
// init: padded uA, uB (culled regions rely on init values in BOTH) and fP
// ---------------------------------------------------------------------------
__global__ __launch_bounds__(256) void eik_init(const float* __restrict__ u0,
                                                const float* __restrict__ f,
                                                float* __restrict__ uA,
                                                float* __restrict__ uB,
                                                float* __restrict__ fP) {
    const int i = blockIdx.x * 256 + threadIdx.x;
    if (i >= PADDED_TOTAL) return;
    const int x = i & 127;
    const int r = i >> 7;          // r = z*132 + y
    const int y = r % 132;
    const int z = r / 132;
    float uv = GBIG, fv = 0.0f;
    if (y >= 2 && y <= 129 && z >= 2 && z <= 129) {
        const int src = ((z - 2) * GN + (y - 2)) * GN + x;
        uv = u0[src];
        fv = f[src];
    }
    uA[i] = uv;
    uB[i] = uv;
    fP[i] = fv;
}

__device__ __forceinline__ float eik_solve(float ax, float ay, float az,
                                           float fh, float uc) {
    const float a1 = fminf(fminf(ax, ay), az);
    const float a3 = fmaxf(fmaxf(ax, ay), az);
    const float a2 = fmaxf(fminf(fmaxf(ax, ay), az), fminf(ax, ay));
    const float x1 = a1 + fh;
    const float d12 = a1 - a2;
    const float disc2 = 2.0f * fh * fh - d12 * d12;
    const float x2 = 0.5f * (a1 + a2 + sqrtf(fmaxf(disc2, 0.0f)));
    const float s = a1 + a2 + a3;
    const float q = a1 * a1 + a2 * a2 + a3 * a3;
    const float disc3 = s * s - 3.0f * (q - fh * fh);
    const float x3 = (s + sqrtf(fmaxf(disc3, 0.0f))) * (1.0f / 3.0f);
    const float xv = (x1 <= a2) ? x1 : ((x2 <= a3) ? x2 : x3);
    return fminf(uc, xv);
}

// ---------------------------------------------------------------------------
// Fused 2-step Jacobi sweep. Block = 256 flat threads, grid (2, 8, 32).
// Stage tile+2 halo into LDS, step1 -> LDS region (tile+1), step2 -> global.
// iter2 = index of the SECOND step this launch performs (for the cull).
// ---------------------------------------------------------------------------
__global__ __launch_bounds__(256, 2) void eik_fused2(const float* __restrict__ uin,
                                                     const float* __restrict__ fP,
                                                     float* __restrict__ uout,
                                                     int iter2) {
    const int x0  = blockIdx.x * 64;   // {0, 64}
    const int gy0 = blockIdx.y * 16;
    const int gz0 = blockIdx.z * 4;

    // Exact cull: tile cells can only have changed by step iter2 if their L1
    // distance to the source (64,64,64) is <= iter2.
    const int dx = (x0 <= 64 && 64 <= x0 + 63) ? 0 : min(abs(x0 - 64), abs(x0 + 63 - 64));
    const int dy = (gy0 <= 64 && 64 <= gy0 + 15) ? 0 : min(abs(gy0 - 64), abs(gy0 + 15 - 64));
    const int dz = (gz0 <= 64 && 64 <= gz0 + 3) ? 0 : min(abs(gz0 - 64), abs(gz0 + 3 - 64));
    if (dx + dy + dz > iter2) return;

    extern __shared__ float smem[];
    float* s_in = smem;            // [D_IN][H_IN][W_IN]
    float* s_r1 = smem + N_IN;     // [D1][H1][W1]

    const int tid = threadIdx.x;

    // ---- stage input region: x window [x0-4, x0+67], y [gy0-2, gy0+17],
    // ---- z [gz0-2, gz0+5]; y/z handled by global BIG padding, x masked.
    for (int s = tid; s < (W_IN / 4) * H_IN * D_IN; s += 256) {  // 2880 f4
        const int j   = s % (W_IN / 4);       // 0..17, float4 within row
        const int row = s / (W_IN / 4);
        const int ry  = row % H_IN;           // 0..19
        const int rz  = row / H_IN;           // 0..7
        float4 v;
        const bool oob = (x0 == 0 && j == 0) || (x0 == 64 && j == 17);
        if (oob) {
            v = make_float4(GBIG, GBIG, GBIG, GBIG);
        } else {
            const int g = ((gz0 + rz) * PPY + (gy0 + ry)) * PITCH_Y + x0 - 4 + 4 * j;
            v = *(const float4*)(uin + g);
        }
        *(float4*)(s_in + (rz * H_IN + ry) * W_IN + 4 * j) = v;
    }
    __syncthreads();

    // ---- step 1: compute region1 = tile + 1 halo: x [x0-2, x0+65] (68 wide),
    // ---- y [gy0-1, gy0+16], z [gz0-1, gz0+4]. Outside-grid cells -> BIG.
    for (int s = tid; s < W1 * H1 * D1; s += 256) {   // 7344 cells
        const int xo = s % W1;                // 0..67  (R4 BUG: was % 66)
        const int t  = s / W1;
        const int yo = t % H1;
        const int zo = t / H1;
        const int x = x0 - 2 + xo;
        const int y = gy0 - 1 + yo;
        const int z = gz0 - 1 + zo;

        const int xi = xo + 2, yi = yo + 1, zi = zo + 1;   // input-region coords
        const float c  = s_in[(zi * H_IN + yi) * W_IN + xi];
        const float ax = fminf(s_in[(zi * H_IN + yi) * W_IN + xi - 1],
                               s_in[(zi * H_IN + yi) * W_IN + xi + 1]);
        const float ay = fminf(s_in[(zi * H_IN + yi - 1) * W_IN + xi],
                               s_in[(zi * H_IN + yi + 1) * W_IN + xi]);
        const float az = fminf(s_in[((zi - 1) * H_IN + yi) * W_IN + xi],
                               s_in[((zi + 1) * H_IN + yi) * W_IN + xi]);

        const bool inside = ((unsigned)x < GN) & ((unsigned)y < GN) & ((unsigned)z < GN);
        // f read is always in-array (padded planes exist); value only used if inside.
        const float fh = fP[((z + 2) * PPY + (y + 2)) * PITCH_Y + (x & 127)];
        const float val = inside ? eik_solve(ax, ay, az, fh, c) : GBIG;
        s_r1[(zo * H1 + yo) * W1 + xo] = val;
    }
    __syncthreads();

    // ---- step 2: compute the tile from region1, write to global.
    for (int s = tid; s < 64 * 16 * 4; s += 256) {    // 4096 cells
        const int xf = s & 63;
        const int yf = (s >> 6) & 15;
        const int zf = s >> 10;
        const int xo = xf + 2, yo = yf + 1, zo = zf + 1;  // region1 coords

        const float c  = s_r1[(zo * H1 + yo) * W1 + xo];
        const float ax = fminf(s_r1[(zo * H1 + yo) * W1 + xo - 1],
                               s_r1[(zo * H1 + yo) * W1 + xo + 1]);
        const float ay = fminf(s_r1[(zo * H1 + yo - 1) * W1 + xo],
                               s_r1[(zo * H1 + yo + 1) * W1 + xo]);
        const float az = fminf(s_r1[((zo - 1) * H1 + yo) * W1 + xo],
                               s_r1[((zo + 1) * H1 + yo) * W1 + xo]);

        const int x = x0 + xf, y = gy0 + yf, z = gz0 + zf;
        const int g = ((z + 2) * PPY + (y + 2)) * PITCH_Y + x;
        const float fh = fP[g];
        uout[g] = eik_solve(ax, ay, az, fh, c);
    }
}

// ---------------------------------------------------------------------------
// Fallback path (R1-proven structure, constants adjusted to +/-2 padding).
// ---------------------------------------------------------------------------
__global__ __launch_bounds__(256) void eik_step(const float* __restrict__ uin,
                                                const float* __restrict__ fP,
                                                float* __restrict__ uout,
                                                int iter) {
    const int lx = threadIdx.x;
    const int gy = blockIdx.y * 8 + threadIdx.y;
    const int gz = blockIdx.z;
    const int x0 = 4 * lx;
    const int dxm = (x0 <= 64 && 64 <= x0 + 3) ? 0 : min(abs(x0 - 64), abs(x0 + 3 - 64));
    const int d = dxm + abs(gy - 64) + abs(gz - 64);
    if (d > iter) return;

    const int base = ((gz + 2) * PPY + (gy + 2)) * PITCH_Y + x0;
    const float4 cc = *(const float4*)(uin + base);
    float xm_s = uin[base - 1];
    float xp_s = uin[base + 4];
    if (lx == 0)  xm_s = GBIG;
    if (lx == 31) xp_s = GBIG;
    const float4 ym = *(const float4*)(uin + base - PITCH_Y);
    const float4 yp = *(const float4*)(uin + base + PITCH_Y);
    const float4 zm = *(const float4*)(uin + base - PITCH_Z);
    const float4 zp = *(const float4*)(uin + base + PITCH_Z);
    const float4 ff = *(const float4*)(fP + base);

    float4 r;
    r.x = eik_solve(fminf(xm_s, cc.y), fminf(ym.x, yp.x), fminf(zm.x, zp.x), ff.x, cc.x);
    r.y = eik_solve(fminf(cc.x, cc.z), fminf(ym.y, yp.y), fminf(zm.y, zp.y), ff.y, cc.y);
    r.z = eik_solve(fminf(cc.y, cc.w), fminf(ym.z, yp.z), fminf(zm.z, zp.z), ff.z, cc.z);
    r.w = eik_solve(fminf(cc.z, xp_s), fminf(ym.w, yp.w), fminf(zm.w, zp.w), ff.w, cc.w);
    *(float4*)(uout + base) = r;
}

__global__ __launch_bounds__(256) void eik_extract(const float* __restrict__ uf,
                                                   float* __restrict__ out) {
    const int j = blockIdx.x * 256 + threadIdx.x;   // 524288 float4s
    const int x4 = j & 31;
    const int y  = (j >> 5) & 127;
    const int z  = j >> 12;
    const float4 v = *(const float4*)(uf + ((z + 2) * PPY + (y + 2)) * PITCH_Y + 4 * x4);
    *(float4*)(out + 4 * j) = v;
}

extern "C" void kernel_launch(void* const* d_in, const int* in_sizes, int n_in,
                              void* d_out, int out_size, void* d_ws, size_t ws_size,
                              hipStream_t stream) {
    const float* u0 = (const float*)d_in[0];
    const float* f  = (const float*)d_in[1];
    float* out = (float*)d_out;

    float* uA = (float*)d_ws;                    // 8.92 MB each
    float* uB = uA + PADDED_TOTAL;
    float* fP = uB + PADDED_TOTAL;

    {
        const int nb = (PADDED_TOTAL + 255) / 256;
        eik_init<<<nb, 256, 0, stream>>>(u0, f, uA, uB, fP);
    }

    // Opt-in to >64 KB dynamic LDS (idempotent, host-side metadata only).
    hipError_t aerr = hipFuncSetAttribute(
        reinterpret_cast<const void*>(eik_fused2),
        hipFuncAttributeMaxDynamicSharedMemorySize, LDS_BYTES);

    if (aerr == hipSuccess) {
        // 64 fused launches, 2 Jacobi steps each. Ping-pong: odd L reads uA.
        const dim3 grid(2, 8, 32);   // 512 blocks -> 2 blocks/CU
        const dim3 block(256, 1, 1);
        for (int L = 1; L <= NITER / 2; ++L) {
            const float* in = (L & 1) ? uA : uB;
            float* o        = (L & 1) ? uB : uA;
            eik_fused2<<<grid, block, LDS_BYTES, stream>>>(in, fP, o, 2 * L);
        }
        // 64 launches (even) -> final state in uA.
        eik_extract<<<GN * GN * GN / 4 / 256, 256, 0, stream>>>(uA, out);
    } else {
        // R1-proven fallback: one launch per sweep.
        const dim3 block(32, 8, 1);
        const dim3 grid(1, 16, 128);
        for (int i = 1; i <= NITER; ++i) {
            const float* in = (i & 1) ? uA : uB;
            float* o        = (i & 1) ? uB : uA;
            eik_step<<<grid, block, 0, stream>>>(in, fP, o, i);
        }
        eik_extract<<<GN * GN * GN / 4 / 256, 256, 0, stream>>>(uA, out);
    }
}

// Round 7
// 1210.307 us; speedup vs baseline: 11.0341x; 1.3722x over previous
//
#include <hip/hip_runtime.h>

#define GN    128
#define GBIG  1.0e5f
#define NITER 128

// Padded layout: x pitch 128 (contiguous rows, no x padding), y,z padded to
// 132 with TWO planes of BIG each side (T=2 fusion needs a +/-2 window).
// Interior cell (x,y,z) -> ((z+2)*132 + (y+2))*128 + x.
#define PPY     132
#define PITCH_Y 128
#define PITCH_Z (128 * 132)
#define PADDED_TOTAL (132 * 132 * 128)

// Fused tile: FULL x width (128) x 8(y) x 4(z) -> no x-halo at all.
// LDS staged input: 128 x 12 x 8 = 12288 floats (48 KB)
// LDS step-1 result: 128 x 10 x 6 =  7680 floats (30 KB)
#define N_IN 12288
#define N_R1 7680
#define LDS_BYTES ((N_IN + N_R1) * 4)   // 79872 B -> 2 blocks/CU (159.7/160 KB)

// ---------------------------------------------------------------------------
// init: padded uA, uB (culled regions rely on init values in BOTH) and fP
// ---------------------------------------------------------------------------
__global__ __launch_bounds__(256) void eik_init(const float* __restrict__ u0,
                                                const float* __restrict__ f,
                                                float* __restrict__ uA,
                                                float* __restrict__ uB,
                                                float* __restrict__ fP) {
    const int i = blockIdx.x * 256 + threadIdx.x;
    if (i >= PADDED_TOTAL) return;
    const int x = i & 127;
    const int r = i >> 7;          // r = z*132 + y
    const int y = r % 132;
    const int z = r / 132;
    float uv = GBIG, fv = 0.0f;
    if (y >= 2 && y <= 129 && z >= 2 && z <= 129) {
        const int src = ((z - 2) * GN + (y - 2)) * GN + x;
        uv = u0[src];
        fv = f[src];
    }
    uA[i] = uv;
    uB[i] = uv;
    fP[i] = fv;
}

__device__ __forceinline__ float eik_solve(float ax, float ay, float az,
                                           float fh, float uc) {
    const float a1 = fminf(fminf(ax, ay), az);
    const float a3 = fmaxf(fmaxf(ax, ay), az);
    const float a2 = fmaxf(fminf(fmaxf(ax, ay), az), fminf(ax, ay));
    const float x1 = a1 + fh;
    const float d12 = a1 - a2;
    const float disc2 = 2.0f * fh * fh - d12 * d12;
    const float x2 = 0.5f * (a1 + a2 + sqrtf(fmaxf(disc2, 0.0f)));
    const float s = a1 + a2 + a3;
    const float q = a1 * a1 + a2 * a2 + a3 * a3;
    const float disc3 = s * s - 3.0f * (q - fh * fh);
    const float x3 = (s + sqrtf(fmaxf(disc3, 0.0f))) * (1.0f / 3.0f);
    const float xv = (x1 <= a2) ? x1 : ((x2 <= a3) ? x2 : x3);
    return fminf(uc, xv);
}

__device__ __forceinline__ float4 eik_solve4(float4 c, float xm_s, float xp_s,
                                             float4 ym, float4 yp,
                                             float4 zm, float4 zp, float4 f4) {
    float4 r;
    r.x = eik_solve(fminf(xm_s, c.y), fminf(ym.x, yp.x), fminf(zm.x, zp.x), f4.x, c.x);
    r.y = eik_solve(fminf(c.x, c.z), fminf(ym.y, yp.y), fminf(zm.y, zp.y), f4.y, c.y);
    r.z = eik_solve(fminf(c.y, c.w), fminf(ym.z, yp.z), fminf(zm.z, zp.z), f4.z, c.z);
    r.w = eik_solve(fminf(c.z, xp_s), fminf(ym.w, yp.w), fminf(zm.w, zp.w), f4.w, c.w);
    return r;
}

// ---------------------------------------------------------------------------
// Fused 2-step Jacobi sweep, fully float4-vectorized LDS traffic.
// Block = 256 flat threads; tile 128 x 8 x 4 at (0, (by0+by)*8, (bz0+bz)*4).
// iter2 = index of the SECOND step performed this launch (for the cull).
// ---------------------------------------------------------------------------
__global__ __launch_bounds__(256, 2) void eik_fused2(const float* __restrict__ uin,
                                                     const float* __restrict__ fP,
                                                     float* __restrict__ uout,
                                                     int iter2, int by0, int bz0) {
    const int gy0 = (blockIdx.y + by0) * 8;
    const int gz0 = (blockIdx.z + bz0) * 4;

    // Exact cull (x spans the source, so dx = 0 always).
    const int dy = (gy0 <= 64 && 64 <= gy0 + 7) ? 0 : min(abs(gy0 - 64), abs(gy0 + 7 - 64));
    const int dz = (gz0 <= 64 && 64 <= gz0 + 3) ? 0 : min(abs(gz0 - 64), abs(gz0 + 3 - 64));
    if (dy + dz > iter2) return;

    extern __shared__ float smem[];
    float* s_in = smem;           // [8][12][128]  z-rows x y-rows x x
    float* s_r1 = smem + N_IN;    // [6][10][128]

    const int tid = threadIdx.x;

    // ---- stage input region y [gy0-2, gy0+9], z [gz0-2, gz0+5], all x.
    // Padded y/z index = grid + 2, so padded row base = (gz0+rz, gy0+ry).
    #pragma unroll
    for (int s = tid; s < 3072; s += 256) {   // 12 float4s per thread
        const int xg = s & 31;
        const int t  = s >> 5;                // 0..95: ry = t%12, rz = t/12
        const int ry = t % 12;
        const int rz = t / 12;
        const int g = ((gz0 + rz) * PPY + (gy0 + ry)) * PITCH_Y + 4 * xg;
        *(float4*)(s_in + t * 128 + 4 * xg) = *(const float4*)(uin + g);
    }
    __syncthreads();

    // ---- step 1: region1 = all x, y [gy0-1, gy0+8], z [gz0-1, gz0+4].
    for (int s = tid; s < 1920; s += 256) {   // 32 x 10 x 6 float4 groups
        const int xg = s & 31;
        const int t  = s >> 5;                // 0..59
        const int yo = t % 10;
        const int zo = t / 10;
        const int y = gy0 - 1 + yo;           // may be -1 or 128 (outside)
        const int z = gz0 - 1 + zo;

        const int ii = ((zo + 1) * 12 + (yo + 1)) * 128 + 4 * xg;  // s_in idx
        const float4 c = *(float4*)(s_in + ii);
        const float xm = (xg == 0)  ? GBIG : s_in[ii - 1];
        const float xp = (xg == 31) ? GBIG : s_in[ii + 4];
        const float4 ym = *(float4*)(s_in + ii - 128);
        const float4 yp = *(float4*)(s_in + ii + 128);
        const float4 zm = *(float4*)(s_in + ii - 12 * 128);
        const float4 zp = *(float4*)(s_in + ii + 12 * 128);
        const float4 ff = *(const float4*)(fP + ((z + 2) * PPY + (y + 2)) * PITCH_Y + 4 * xg);

        float4 r = eik_solve4(c, xm, xp, ym, yp, zm, zp, ff);
        // Cells outside the grid must stay BIG (they are padding for step 2).
        if (((unsigned)y >= 128u) | ((unsigned)z >= 128u))
            r = make_float4(GBIG, GBIG, GBIG, GBIG);
        *(float4*)(s_r1 + (zo * 10 + yo) * 128 + 4 * xg) = r;
    }
    __syncthreads();

    // ---- step 2: the 128 x 8 x 4 tile from region1, write to global.
    #pragma unroll
    for (int s = tid; s < 1024; s += 256) {   // 4 float4 groups per thread
        const int xg = s & 31;
        const int t  = s >> 5;                // 0..31: yf = t&7, zf = t>>3
        const int yf = t & 7;
        const int zf = t >> 3;

        const int ri = ((zf + 1) * 10 + (yf + 1)) * 128 + 4 * xg;
        const float4 c = *(float4*)(s_r1 + ri);
        const float xm = (xg == 0)  ? GBIG : s_r1[ri - 1];
        const float xp = (xg == 31) ? GBIG : s_r1[ri + 4];
        const float4 ym = *(float4*)(s_r1 + ri - 128);
        const float4 yp = *(float4*)(s_r1 + ri + 128);
        const float4 zm = *(float4*)(s_r1 + ri - 10 * 128);
        const float4 zp = *(float4*)(s_r1 + ri + 10 * 128);

        const int g = ((gz0 + zf + 2) * PPY + (gy0 + yf + 2)) * PITCH_Y + 4 * xg;
        const float4 ff = *(const float4*)(fP + g);
        *(float4*)(uout + g) = eik_solve4(c, xm, xp, ym, yp, zm, zp, ff);
    }
}

// ---------------------------------------------------------------------------
// Fallback path (R1-proven structure, +/-2 padding).
// ---------------------------------------------------------------------------
__global__ __launch_bounds__(256) void eik_step(const float* __restrict__ uin,
                                                const float* __restrict__ fP,
                                                float* __restrict__ uout,
                                                int iter) {
    const int lx = threadIdx.x;
    const int gy = blockIdx.y * 8 + threadIdx.y;
    const int gz = blockIdx.z;
    const int x0 = 4 * lx;
    const int dxm = (x0 <= 64 && 64 <= x0 + 3) ? 0 : min(abs(x0 - 64), abs(x0 + 3 - 64));
    const int d = dxm + abs(gy - 64) + abs(gz - 64);
    if (d > iter) return;

    const int base = ((gz + 2) * PPY + (gy + 2)) * PITCH_Y + x0;
    const float4 cc = *(const float4*)(uin + base);
    float xm_s = uin[base - 1];
    float xp_s = uin[base + 4];
    if (lx == 0)  xm_s = GBIG;
    if (lx == 31) xp_s = GBIG;
    const float4 ym = *(const float4*)(uin + base - PITCH_Y);
    const float4 yp = *(const float4*)(uin + base + PITCH_Y);
    const float4 zm = *(const float4*)(uin + base - PITCH_Z);
    const float4 zp = *(const float4*)(uin + base + PITCH_Z);
    const float4 ff = *(const float4*)(fP + base);
    *(float4*)(uout + base) = eik_solve4(cc, xm_s, xp_s, ym, yp, zm, zp, ff);
}

__global__ __launch_bounds__(256) void eik_extract(const float* __restrict__ uf,
                                                   float* __restrict__ out) {
    const int j = blockIdx.x * 256 + threadIdx.x;   // 524288 float4s
    const int x4 = j & 31;
    const int y  = (j >> 5) & 127;
    const int z  = j >> 12;
    const float4 v = *(const float4*)(uf + ((z + 2) * PPY + (y + 2)) * PITCH_Y + 4 * x4);
    *(float4*)(out + 4 * j) = v;
}

extern "C" void kernel_launch(void* const* d_in, const int* in_sizes, int n_in,
                              void* d_out, int out_size, void* d_ws, size_t ws_size,
                              hipStream_t stream) {
    const float* u0 = (const float*)d_in[0];
    const float* f  = (const float*)d_in[1];
    float* out = (float*)d_out;

    float* uA = (float*)d_ws;                    // 8.92 MB each
    float* uB = uA + PADDED_TOTAL;
    float* fP = uB + PADDED_TOTAL;

    {
        const int nb = (PADDED_TOTAL + 255) / 256;
        eik_init<<<nb, 256, 0, stream>>>(u0, f, uA, uB, fP);
    }

    // Opt-in to >64 KB dynamic LDS (host-side metadata, idempotent).
    hipError_t aerr = hipFuncSetAttribute(
        reinterpret_cast<const void*>(eik_fused2),
        hipFuncAttributeMaxDynamicSharedMemorySize, LDS_BYTES);

    if (aerr == hipSuccess) {
        // 64 fused launches, 2 Jacobi steps each, grid trimmed to the
        // bounding box of ball(2L) in block units (kernel cull does corners).
        for (int L = 1; L <= NITER / 2; ++L) {
            const int R = 2 * L;
            const int by_lo = (R >= 57) ? 0 : (57 - R + 7) / 8;  // gy0+7 >= 64-R
            const int by_hi = min(15, (64 + R) / 8);             // gy0   <= 64+R
            const int bz_lo = (R >= 61) ? 0 : (61 - R + 3) / 4;  // gz0+3 >= 64-R
            const int bz_hi = min(31, (64 + R) / 4);             // gz0   <= 64+R
            const dim3 grid(1, by_hi - by_lo + 1, bz_hi - bz_lo + 1);
            const float* in = (L & 1) ? uA : uB;
            float* o        = (L & 1) ? uB : uA;
            eik_fused2<<<grid, dim3(256, 1, 1), LDS_BYTES, stream>>>(
                in, fP, o, R, by_lo, bz_lo);
        }
        // 64 fused launches (even count) -> final state in uA.
        eik_extract<<<GN * GN * GN / 4 / 256, 256, 0, stream>>>(uA, out);
    } else {
        // R1-proven fallback: one launch per sweep.
        const dim3 block(32, 8, 1);
        const dim3 grid(1, 16, 128);
        for (int i = 1; i <= NITER; ++i) {
            const float* in = (i & 1) ? uA : uB;
            float* o        = (i & 1) ? uB : uA;
            eik_step<<<grid, block, 0, stream>>>(in, fP, o, i);
        }
        eik_extract<<<GN * GN * GN / 4 / 256, 256, 0, stream>>>(uA, out);
    }
}